// Round 13
// baseline (390.533 us; speedup 1.0000x reference)
//
#include <hip/hip_runtime.h>
#include <hip/hip_fp16.h>
#include <math.h>

#define N_NODES 50000
#define N_EDGES 800000
#define NEG 0.2f

// ---------------- CSR build ----------------

__global__ void zero_kernel(int* a, int n) {
    int i = blockIdx.x * blockDim.x + threadIdx.x;
    if (i < n) a[i] = 0;
}

__global__ void count_kernel(const int* __restrict__ dst, int* cnt, int E) {
    int i = blockIdx.x * blockDim.x + threadIdx.x;
    if (i < E) atomicAdd(&cnt[dst[i]], 1);
}

// multi-block scan: per-block exclusive scan of 256 elements + block total
__global__ void scan1_kernel(const int* __restrict__ cnt, int* rowptr, int* partials, int n) {
    __shared__ int sh[256];
    int tid = threadIdx.x;
    int i = blockIdx.x * 256 + tid;
    int v = (i < n) ? cnt[i] : 0;
    sh[tid] = v;
    __syncthreads();
    for (int off = 1; off < 256; off <<= 1) {
        int t = (tid >= off) ? sh[tid - off] : 0;
        __syncthreads();
        sh[tid] += t;
        __syncthreads();
    }
    if (i < n) rowptr[i] = sh[tid] - v;  // exclusive within block
    if (tid == 255) partials[blockIdx.x] = sh[255];
}

__global__ void scan2_kernel(int* partials, int nb) {
    __shared__ int sh[256];
    int tid = threadIdx.x;
    int v = (tid < nb) ? partials[tid] : 0;
    sh[tid] = v;
    __syncthreads();
    for (int off = 1; off < 256; off <<= 1) {
        int t = (tid >= off) ? sh[tid - off] : 0;
        __syncthreads();
        sh[tid] += t;
        __syncthreads();
    }
    if (tid < nb) partials[tid] = sh[tid] - v;  // exclusive
}

__global__ void scan3_kernel(int* rowptr, const int* __restrict__ partials, int n) {
    int i = blockIdx.x * blockDim.x + threadIdx.x;
    if (i < n) rowptr[i] += partials[i >> 8];
    if (i == 0) rowptr[n] = N_EDGES;
}

// fill CSR; reuse cnt (still holds counts) via atomicSub -> no fillc array
__global__ void fill_kernel(const int* __restrict__ src, const int* __restrict__ dst,
                            const int* __restrict__ rowptr, int* cnt, int* col, int E) {
    int i = blockIdx.x * blockDim.x + threadIdx.x;
    if (i < E) {
        int d = dst[i];
        int pos = rowptr[d] + atomicSub(&cnt[d], 1) - 1;
        col[pos] = src[i];
    }
}

// ---------------- GEMM: A[rows,K] @ W[K,192] -> h16[rows,192] (fp16 out)
// fused epilogue: as4/ad4/wself4 (att dots + self-loop weight) per row.
// 256 thr, 32-row x 192-col tile, 2x12 acc/thread; KT=16 (LDS 14.6KB).
// xs[16][34]: staging writes hit 32 distinct banks (conflict-free);
// k-ascending fp32 accumulation order identical to the validated round-5 gemm.
template <int K>
__global__ __launch_bounds__(256) void gemm_kernel(const float* __restrict__ A,
                                                   const float* __restrict__ W,
                                                   __half* __restrict__ out,
                                                   const float* __restrict__ att_src,
                                                   const float* __restrict__ att_dst,
                                                   float* __restrict__ as4,
                                                   float* __restrict__ ad4,
                                                   float* __restrict__ wself4, int rows) {
    constexpr int KT = 16;
    __shared__ float xs[KT][34];   // transposed x-tile, 32 rows + 2 pad
    __shared__ float ws[KT][192];
    int tid = threadIdx.x;
    int tx = tid & 15;             // col group: cols tx*12 .. +11
    int ty = tid >> 4;             // row group: rows ty*2 .. +1
    int row0 = blockIdx.x * 32;

    float acc[2][12];
#pragma unroll
    for (int r = 0; r < 2; ++r)
#pragma unroll
        for (int c = 0; c < 12; ++c) acc[r][c] = 0.f;

    for (int kt = 0; kt < K; kt += KT) {
        // stage x tile (transposed): xs[kk][r] = A[row0+r][kt+kk]
        // lanes: kk=idx&15, r=idx>>4 -> bank (2kk+r)%32: 32 lanes, 32 banks
#pragma unroll
        for (int idx = tid; idx < 32 * KT; idx += 256) {
            int kk = idx & 15, r = idx >> 4;
            int rr = row0 + r;
            xs[kk][r] = (rr < rows) ? A[rr * K + kt + kk] : 0.f;
        }
        // stage W tile (stride-1 writes, conflict-free)
#pragma unroll
        for (int idx = tid; idx < KT * 192; idx += 256) {
            int kk = idx / 192, c = idx - kk * 192;
            ws[kk][c] = W[(kt + kk) * 192 + c];
        }
        __syncthreads();
#pragma unroll
        for (int k = 0; k < KT; ++k) {
            float2 a2 = *(const float2*)&xs[k][ty * 2];
            float4 w0 = *(const float4*)&ws[k][tx * 12];
            float4 w1 = *(const float4*)&ws[k][tx * 12 + 4];
            float4 w2 = *(const float4*)&ws[k][tx * 12 + 8];
            float av[2] = {a2.x, a2.y};
            float wv[12] = {w0.x, w0.y, w0.z, w0.w, w1.x, w1.y, w1.z, w1.w,
                            w2.x, w2.y, w2.z, w2.w};
#pragma unroll
            for (int r = 0; r < 2; ++r)
#pragma unroll
                for (int c = 0; c < 12; ++c) acc[r][c] += av[r] * wv[c];
        }
        __syncthreads();
    }

    // epilogue: h16 store + fused alpha (row's 16 owner threads = contiguous lanes)
    float asr[12], adr[12];
#pragma unroll
    for (int c = 0; c < 12; ++c) {
        asr[c] = att_src[tx * 12 + c];
        adr[c] = att_dst[tx * 12 + c];
    }
#pragma unroll
    for (int r = 0; r < 2; ++r) {
        int rr = row0 + ty * 2 + r;
        bool ok = rr < rows;
        if (ok) {
            __half2* o = (__half2*)(out + (size_t)rr * 192 + tx * 12);
#pragma unroll
            for (int c = 0; c < 6; ++c)
                o[c] = __floats2half2_rn(acc[r][2 * c], acc[r][2 * c + 1]);
        }
        float s0 = 0, s1 = 0, s2 = 0, d0 = 0, d1 = 0, d2 = 0;
#pragma unroll
        for (int c = 0; c < 12; ++c) {
            int cc = tx * 12 + c;
            float p = acc[r][c] * asr[c];
            float q = acc[r][c] * adr[c];
            if (cc < 64)       { s0 += p; d0 += q; }
            else if (cc < 128) { s1 += p; d1 += q; }
            else               { s2 += p; d2 += q; }
        }
        for (int off = 1; off < 16; off <<= 1) {
            s0 += __shfl_xor(s0, off); s1 += __shfl_xor(s1, off); s2 += __shfl_xor(s2, off);
            d0 += __shfl_xor(d0, off); d1 += __shfl_xor(d1, off); d2 += __shfl_xor(d2, off);
        }
        if (tx == 0 && ok) {
            as4[rr * 4 + 0] = s0; as4[rr * 4 + 1] = s1; as4[rr * 4 + 2] = s2;
            ad4[rr * 4 + 0] = d0; ad4[rr * 4 + 1] = d1; ad4[rr * 4 + 2] = d2;
            float v0 = s0 + d0; v0 = v0 > 0.f ? v0 : NEG * v0;
            float v1 = s1 + d1; v1 = v1 > 0.f ? v1 : NEG * v1;
            float v2 = s2 + d2; v2 = v2 > 0.f ? v2 : NEG * v2;
            wself4[rr * 4 + 0] = __expf(v0);
            wself4[rr * 4 + 1] = __expf(v1);
            wself4[rr * 4 + 2] = __expf(v2);
        }
    }
}

// ---------------- aggregation: one wave per node, fp16 gathers, fully-predicated U=8 ----------------
// lane l (0..47): head hl=l>>4, channels (l&15)*4 .. +3 of that head
template <bool RELU>
__global__ __launch_bounds__(256) void aggregate_kernel(const __half* __restrict__ h,
                                                        const float* __restrict__ as_,
                                                        const float* __restrict__ ad4,
                                                        const float* __restrict__ wself4,
                                                        const float* __restrict__ bias,
                                                        const int* __restrict__ rowptr,
                                                        const int* __restrict__ col,
                                                        float* __restrict__ out, int n) {
    constexpr int U = 8;
    __shared__ float sh[4][192];
    int wid = (int)((blockIdx.x * blockDim.x + threadIdx.x) >> 6);
    int l = threadIdx.x & 63;
    int wv = threadIdx.x >> 6;
    bool valid = wid < n;
    int d = valid ? wid : 0;
    if (valid && l < 48) {
        int hl = l >> 4;
        int r0 = rowptr[d], r1 = rowptr[d + 1];
        float adh = ad4[d * 4 + hl];
        float w = wself4[d * 4 + hl];
        float2 sraw = *(const float2*)(h + (size_t)d * 192 + l * 4);
        float2 s01 = __half22float2(*(__half2*)&sraw.x);
        float2 s23 = __half22float2(*(__half2*)&sraw.y);
        float ax = w * s01.x, ay = w * s01.y, az = w * s23.x, aw = w * s23.y;
        float den = w;

        for (int j = r0; j < r1; j += U) {
            int s[U];
            bool act[U];
            float av[U];
            float2 g[U];
#pragma unroll
            for (int u = 0; u < U; ++u) {
                int jj = j + u;
                act[u] = jj < r1;
                s[u] = act[u] ? col[jj] : 0;
            }
#pragma unroll
            for (int u = 0; u < U; ++u) {
                float t = as_[s[u] * 4 + hl];
                av[u] = act[u] ? t : -1e30f;
            }
#pragma unroll
            for (int u = 0; u < U; ++u)
                g[u] = *(const float2*)(h + (size_t)s[u] * 192 + l * 4);
#pragma unroll
            for (int u = 0; u < U; ++u) {
                float v = av[u] + adh;
                v = v > 0.f ? v : NEG * v;
                float we = __expf(v);
                float2 g01 = __half22float2(*(__half2*)&g[u].x);
                float2 g23 = __half22float2(*(__half2*)&g[u].y);
                den += we;
                ax += we * g01.x;
                ay += we * g01.y;
                az += we * g23.x;
                aw += we * g23.y;
            }
        }
        float r = 1.f / den;
        float4 o = {ax * r, ay * r, az * r, aw * r};
        *(float4*)&sh[wv][l * 4] = o;
    }
    __syncthreads();
    if (valid) {
        float o = (sh[wv][l] + sh[wv][64 + l] + sh[wv][128 + l]) * (1.f / 3.f) + bias[l];
        if (RELU) o = fmaxf(o, 0.f);
        out[(size_t)d * 64 + l] = o;
    }
}

extern "C" void kernel_launch(void* const* d_in, const int* in_sizes, int n_in,
                              void* d_out, int out_size, void* d_ws, size_t ws_size,
                              hipStream_t stream) {
    const float* x = (const float*)d_in[0];       // [N,128]
    const int* ei = (const int*)d_in[1];          // [2,E]
    const float* W1 = (const float*)d_in[2];      // [128,192]
    const float* att_s1 = (const float*)d_in[3];  // [3,64] -> flat 192
    const float* att_d1 = (const float*)d_in[4];
    const float* b1 = (const float*)d_in[5];      // [64]
    const float* W2 = (const float*)d_in[6];      // [64,192]
    const float* att_s2 = (const float*)d_in[7];
    const float* att_d2 = (const float*)d_in[8];
    const float* b2 = (const float*)d_in[9];
    const int* src = ei;
    const int* dst = ei + N_EDGES;

    // workspace layout (16B-aligned blocks) — identical to the validated round-5 kernel
    __half* h16 = (__half*)d_ws;                         // N*192 halves
    float* as4 = (float*)(h16 + (size_t)N_NODES * 192);  // N*4
    float* ad4 = as4 + N_NODES * 4;                      // N*4
    float* wself4 = ad4 + N_NODES * 4;                   // N*4
    int* cnt = (int*)(wself4 + N_NODES * 4);             // N
    int* rowptr = cnt + N_NODES;                         // N+1
    int* col = rowptr + N_NODES + 1;                     // E
    int* partials = col + N_EDGES;                       // <=256

    float* outf = (float*)d_out;                         // doubles as layer-1 output [N,64]
    const int NB = (N_NODES + 255) / 256;

    // CSR build (shared by both layers)
    zero_kernel<<<(N_NODES + 255) / 256, 256, 0, stream>>>(cnt, N_NODES);
    count_kernel<<<(N_EDGES + 255) / 256, 256, 0, stream>>>(dst, cnt, N_EDGES);
    scan1_kernel<<<NB, 256, 0, stream>>>(cnt, rowptr, partials, N_NODES);
    scan2_kernel<<<1, 256, 0, stream>>>(partials, NB);
    scan3_kernel<<<NB, 256, 0, stream>>>(rowptr, partials, N_NODES);
    fill_kernel<<<(N_EDGES + 255) / 256, 256, 0, stream>>>(src, dst, rowptr, cnt, col, N_EDGES);

    // layer 1 (gemm + fused alpha)
    gemm_kernel<128><<<(N_NODES + 31) / 32, 256, 0, stream>>>(x, W1, h16, att_s1, att_d1,
                                                              as4, ad4, wself4, N_NODES);
    aggregate_kernel<true><<<(N_NODES + 3) / 4, 256, 0, stream>>>(h16, as4, ad4, wself4, b1,
                                                                  rowptr, col, outf, N_NODES);

    // layer 2 (reads layer-1 output from d_out, then overwrites d_out)
    gemm_kernel<64><<<(N_NODES + 31) / 32, 256, 0, stream>>>(outf, W2, h16, att_s2, att_d2,
                                                             as4, ad4, wself4, N_NODES);
    aggregate_kernel<false><<<(N_NODES + 3) / 4, 256, 0, stream>>>(h16, as4, ad4, wself4, b2,
                                                                   rowptr, col, outf, N_NODES);
}